// Round 11
// baseline (19.377 us; speedup 1.0000x reference)
//
#include <hip/hip_runtime.h>
#include <hip/hip_bf16.h>

// B=512, N=64, D=128, 4 edge types.
// out[b] = softmax_j(select_k(leakyrelu((h*a_k) @ h^T), adj)) @ h
// R10 algorithm; 128-thread blocks (grid 512) -> 4 blocks/CU for cross-block
// phase overlap. al_lds overlays h_lds (guarded by a 2nd barrier). LDS 35.8KB.

#define NB 512
#define NN 64
#define ND 128
#define HS 136   // h_lds row stride (128 + 8 pad)
#define AS 72    // alpha row stride (overlay inside h_lds region)

typedef __bf16 bf16x8 __attribute__((ext_vector_type(8)));
typedef __bf16 bf16x4 __attribute__((ext_vector_type(4)));
typedef float  f32x4  __attribute__((ext_vector_type(4)));

__global__ __launch_bounds__(128, 2)
void gat_kernel(const float* __restrict__ hidden,
                const int*   __restrict__ adj,
                const float* __restrict__ a,
                float*       __restrict__ out)
{
    __shared__ __bf16 h_lds[NN * HS];       // 17408 B; al_lds overlays after eGEMM
    __shared__ __bf16 h_tr[8 * NN * 16];    // 16384 B  [dt][j][dcol] for tr-read
    __shared__ float  a_lds[4 * ND];        //  2048 B   -> total 35840 B
    __bf16* al_lds = h_lds;                 // overlay: 64*72 = 4608 elems < 64*136

    const int t = threadIdx.x;
    const int l = t & 63;
    const int w = t >> 6;               // wave 0..1
    const int b = blockIdx.x;
    const int g  = l >> 4;              // 16-lane group 0..3
    const int g8 = g << 3;

    // ---- h loads (barrier critical path): 16 float4 in flight ----
    const float4* hin = (const float4*)(hidden + (size_t)b * NN * ND);
    float4 sv[16];
    int srow[16], sc4[16];
    #pragma unroll
    for (int s = 0; s < 16; ++s) {
        srow[s] = ((l >> 2) & 15) | ((s >> 2) << 4);
        int f4  = (l & 3) | (w << 2) | ((s & 3) << 3);
        sc4[s]  = f4 << 2;
        sv[s] = hin[srow[s] * 32 + f4];
    }
    const float av0 = a[t], av1 = a[t + 128], av2 = a[t + 256], av3 = a[t + 384];

    // ---- LDS writes (wait only on the h loads) ----
    #pragma unroll
    for (int s = 0; s < 16; ++s) {
        float4 v = sv[s];
        bf16x4 pk = { (__bf16)v.x, (__bf16)v.y, (__bf16)v.z, (__bf16)v.w };
        *(bf16x4*)&h_lds[srow[s] * HS + sc4[s]] = pk;
        *(bf16x4*)&h_tr[((sc4[s] >> 4) << 10) + (srow[s] << 4) + (sc4[s] & 15)] = pk;
    }
    a_lds[t] = av0; a_lds[t + 128] = av1; a_lds[t + 256] = av2; a_lds[t + 384] = av3;
    __syncthreads();

    // ---- adj loads: 32/thread, stream under eGEMM, consumed after it ----
    const int* adjb = adj + (size_t)b * NN * NN;
    int adjv[2][4][4];
    #pragma unroll
    for (int rt = 0; rt < 2; ++rt)
        #pragma unroll
        for (int ct = 0; ct < 4; ++ct)
            #pragma unroll
            for (int r = 0; r < 4; ++r)
                adjv[rt][ct][r] = adjb[(w * 32 + rt * 16 + g * 4 + r) * NN + ct * 16 + (l & 15)];

    // ---- e-GEMM: wave w owns rows w*32 .. w*32+31 (2 row-tiles) ----
    f32x4 acc[2][4][4];   // [rt][ct][k]
    #pragma unroll
    for (int rt = 0; rt < 2; ++rt)
        #pragma unroll
        for (int ct = 0; ct < 4; ++ct)
            #pragma unroll
            for (int k = 0; k < 4; ++k)
                acc[rt][ct][k] = (f32x4){0.f, 0.f, 0.f, 0.f};

    #pragma unroll
    for (int kk = 0; kk < 4; ++kk) {
        int d0 = kk * 32 + g8;
        bf16x8 hk[2][4];
        #pragma unroll
        for (int rt = 0; rt < 2; ++rt) {
            bf16x8 hf = *(const bf16x8*)&h_lds[(w * 32 + rt * 16 + (l & 15)) * HS + d0];
            float hff[8];
            #pragma unroll
            for (int e = 0; e < 8; ++e) hff[e] = (float)hf[e];
            #pragma unroll
            for (int k = 0; k < 4; ++k) {
                float4 alo = *(const float4*)&a_lds[k * ND + d0];
                float4 ahi = *(const float4*)&a_lds[k * ND + d0 + 4];
                bf16x8 r;
                r[0] = (__bf16)(hff[0] * alo.x); r[1] = (__bf16)(hff[1] * alo.y);
                r[2] = (__bf16)(hff[2] * alo.z); r[3] = (__bf16)(hff[3] * alo.w);
                r[4] = (__bf16)(hff[4] * ahi.x); r[5] = (__bf16)(hff[5] * ahi.y);
                r[6] = (__bf16)(hff[6] * ahi.z); r[7] = (__bf16)(hff[7] * ahi.w);
                hk[rt][k] = r;
            }
        }
        bf16x8 bfr[4];
        #pragma unroll
        for (int ct = 0; ct < 4; ++ct)
            bfr[ct] = *(const bf16x8*)&h_lds[(ct * 16 + (l & 15)) * HS + d0];
        __builtin_amdgcn_s_setprio(1);
        #pragma unroll
        for (int rt = 0; rt < 2; ++rt)
            #pragma unroll
            for (int ct = 0; ct < 4; ++ct)
                #pragma unroll
                for (int k = 0; k < 4; ++k)
                    acc[rt][ct][k] = __builtin_amdgcn_mfma_f32_16x16x32_bf16(hk[rt][k], bfr[ct], acc[rt][ct][k], 0, 0, 0);
        __builtin_amdgcn_s_setprio(0);
    }
    __syncthreads();   // all h_lds reads done -> safe to overlay al_lds

    // ---- PV tr-reads issued NOW; latency hides under the exp epilogue ----
    unsigned trb = (unsigned)(unsigned long long)(&h_tr[0])
                 + (unsigned)(((l & 15) << 3) + (g << 8));
    bf16x4 tr[8][4];
#define TRR(dst, off) asm volatile("ds_read_b64_tr_b16 %0, %1 offset:" #off : "=v"(dst) : "v"(trb));
    TRR(tr[0][0], 0)     TRR(tr[0][1], 128)   TRR(tr[0][2], 1024)  TRR(tr[0][3], 1152)
    TRR(tr[1][0], 2048)  TRR(tr[1][1], 2176)  TRR(tr[1][2], 3072)  TRR(tr[1][3], 3200)
    TRR(tr[2][0], 4096)  TRR(tr[2][1], 4224)  TRR(tr[2][2], 5120)  TRR(tr[2][3], 5248)
    TRR(tr[3][0], 6144)  TRR(tr[3][1], 6272)  TRR(tr[3][2], 7168)  TRR(tr[3][3], 7296)
    TRR(tr[4][0], 8192)  TRR(tr[4][1], 8320)  TRR(tr[4][2], 9216)  TRR(tr[4][3], 9344)
    TRR(tr[5][0], 10240) TRR(tr[5][1], 10368) TRR(tr[5][2], 11264) TRR(tr[5][3], 11392)
    TRR(tr[6][0], 12288) TRR(tr[6][1], 12416) TRR(tr[6][2], 13312) TRR(tr[6][3], 13440)
    TRR(tr[7][0], 14336) TRR(tr[7][1], 14464) TRR(tr[7][2], 15360) TRR(tr[7][3], 15488)
#undef TRR

    // ---- select raw logit by adj, one leakyrelu, exp (no max-sub) -> al ----
    #pragma unroll
    for (int rt = 0; rt < 2; ++rt)
        #pragma unroll
        for (int ct = 0; ct < 4; ++ct)
            #pragma unroll
            for (int r = 0; r < 4; ++r) {
                int av = adjv[rt][ct][r];
                float v = av == 1 ? acc[rt][ct][0][r]
                        : av == 2 ? acc[rt][ct][1][r]
                        : av == 3 ? acc[rt][ct][2][r]
                        : av == 4 ? acc[rt][ct][3][r] : -9.0e15f;
                v = fmaxf(v, 0.2f * v);
                float p = __expf(v);
                al_lds[(w * 32 + rt * 16 + g * 4 + r) * AS + ct * 16 + (l & 15)] = (__bf16)p;
            }

    // ---- P fragments + rowsum via ones-MFMA per row-tile ----
    bf16x8 ones;
    #pragma unroll
    for (int e = 0; e < 8; ++e) ones[e] = (__bf16)1.0f;
    bf16x8 aA0[2], aA1[2];
    float inv[2][4];
    #pragma unroll
    for (int rt = 0; rt < 2; ++rt) {
        int ia = w * 32 + rt * 16 + (l & 15);
        aA0[rt] = *(const bf16x8*)&al_lds[ia * AS + g8];
        aA1[rt] = *(const bf16x8*)&al_lds[ia * AS + 32 + g8];
        f32x4 sacc = {0.f, 0.f, 0.f, 0.f};
        sacc = __builtin_amdgcn_mfma_f32_16x16x32_bf16(aA0[rt], ones, sacc, 0, 0, 0);
        sacc = __builtin_amdgcn_mfma_f32_16x16x32_bf16(aA1[rt], ones, sacc, 0, 0, 0);
        #pragma unroll
        for (int r = 0; r < 4; ++r) inv[rt][r] = __builtin_amdgcn_rcpf(sacc[r]);
    }

    asm volatile("s_waitcnt lgkmcnt(0)" ::: "memory");
    __builtin_amdgcn_sched_barrier(0);

    // ---- PV MFMAs + stores ----
    float* outb = out + (size_t)b * NN * ND;
    #pragma unroll
    for (int dt = 0; dt < 8; ++dt) {
        bf16x8 B0 = __builtin_shufflevector(tr[dt][0], tr[dt][1], 0, 1, 2, 3, 4, 5, 6, 7);
        bf16x8 B1 = __builtin_shufflevector(tr[dt][2], tr[dt][3], 0, 1, 2, 3, 4, 5, 6, 7);
        int dr = dt * 16 + (l & 15);
        #pragma unroll
        for (int rt = 0; rt < 2; ++rt) {
            __builtin_amdgcn_s_setprio(1);
            f32x4 o = {0.f, 0.f, 0.f, 0.f};
            o = __builtin_amdgcn_mfma_f32_16x16x32_bf16(aA0[rt], B0, o, 0, 0, 0);
            o = __builtin_amdgcn_mfma_f32_16x16x32_bf16(aA1[rt], B1, o, 0, 0, 0);
            __builtin_amdgcn_s_setprio(0);
            #pragma unroll
            for (int r = 0; r < 4; ++r)
                outb[(w * 32 + rt * 16 + g * 4 + r) * ND + dr] = o[r] * inv[rt][r];
        }
    }
}

extern "C" void kernel_launch(void* const* d_in, const int* in_sizes, int n_in,
                              void* d_out, int out_size, void* d_ws, size_t ws_size,
                              hipStream_t stream) {
    const float* hidden = (const float*)d_in[0];
    const int*   adj    = (const int*)d_in[1];
    const float* a      = (const float*)d_in[2];
    float*       out    = (float*)d_out;
    gat_kernel<<<NB, 128, 0, stream>>>(hidden, adj, a, out);
}

// Round 12
// 14.784 us; speedup vs baseline: 1.3106x; 1.3106x over previous
//
#include <hip/hip_runtime.h>
#include <hip/hip_bf16.h>

// B=512, N=64, D=128, 4 edge types.
// out[b] = softmax_j(select_k(leakyrelu((h*a_k) @ h^T), adj)) @ h
// R10 (session best: 14.95us): select-then-leaky, no-max exp, ones-MFMA
// rowsum, batched PV tr-reads. Grid 512 x 256thr = 2 blocks/CU, 8 waves/CU.

#define NB 512
#define NN 64
#define ND 128
#define HS 136   // h_lds row stride (128 + 8 pad)
#define AS 72    // alpha row stride

typedef __bf16 bf16x8 __attribute__((ext_vector_type(8)));
typedef __bf16 bf16x4 __attribute__((ext_vector_type(4)));
typedef float  f32x4  __attribute__((ext_vector_type(4)));

__global__ __launch_bounds__(256)
void gat_kernel(const float* __restrict__ hidden,
                const int*   __restrict__ adj,
                const float* __restrict__ a,
                float*       __restrict__ out)
{
    __shared__ __bf16 h_lds[NN * HS];       // 17408 B  row-major, padded
    __shared__ __bf16 h_tr[8 * NN * 16];    // 16384 B  [dt][j][dcol] for tr-read
    __shared__ __bf16 al_lds[NN * AS];      //  9216 B  exp(P) (unnormalized)
    __shared__ float  a_lds[4 * ND];        //  2048 B
                                            //  total 45056 B

    const int t = threadIdx.x;
    const int l = t & 63;
    const int w = t >> 6;
    const int b = blockIdx.x;
    const int g  = l >> 4;              // 16-lane group 0..3
    const int g8 = g << 3;
    const int i0 = w * 16 + (g << 2);   // e-GEMM C/D row base

    // ---- h loads (barrier critical path): 8 float4 in flight ----
    const float4* hin = (const float4*)(hidden + (size_t)b * NN * ND);
    float4 sv[8];
    int srow[8], sc4[8];
    #pragma unroll
    for (int s = 0; s < 8; ++s) {
        srow[s] = ((l >> 2) & 15) | ((s >> 1) << 4);
        int f4  = (l & 3) | (w << 2) | ((s & 1) << 4);
        sc4[s]  = f4 << 2;
        sv[s] = hin[srow[s] * 32 + f4];
    }
    const float av0 = a[t];
    const float av1 = a[t + 256];

    // ---- LDS writes (wait only on the h loads) ----
    #pragma unroll
    for (int s = 0; s < 8; ++s) {
        float4 v = sv[s];
        bf16x4 pk = { (__bf16)v.x, (__bf16)v.y, (__bf16)v.z, (__bf16)v.w };
        *(bf16x4*)&h_lds[srow[s] * HS + sc4[s]] = pk;
        *(bf16x4*)&h_tr[((sc4[s] >> 4) << 10) + (srow[s] << 4) + (sc4[s] & 15)] = pk;
    }
    a_lds[t]       = av0;
    a_lds[t + 256] = av1;
    __syncthreads();   // the only barrier

    // ---- adj loads: stream under eGEMM, consumed after it ----
    const int* adjb = adj + (size_t)b * NN * NN;
    int adjv[4][4];
    #pragma unroll
    for (int ct = 0; ct < 4; ++ct)
        #pragma unroll
        for (int r = 0; r < 4; ++r)
            adjv[ct][r] = adjb[(i0 + r) * NN + ct * 16 + (l & 15)];

    // ---- e-GEMM: e_k = (h*a_k) @ h^T ; wave w owns rows w*16..w*16+15 ----
    const int irow = w * 16 + (l & 15);
    f32x4 acc[4][4];   // [ct][k]
    #pragma unroll
    for (int ct = 0; ct < 4; ++ct)
        #pragma unroll
        for (int k = 0; k < 4; ++k)
            acc[ct][k] = (f32x4){0.f, 0.f, 0.f, 0.f};

    #pragma unroll
    for (int kk = 0; kk < 4; ++kk) {
        int d0 = kk * 32 + g8;
        bf16x8 hf = *(const bf16x8*)&h_lds[irow * HS + d0];
        float hff[8];
        #pragma unroll
        for (int e = 0; e < 8; ++e) hff[e] = (float)hf[e];
        bf16x8 hk[4];
        #pragma unroll
        for (int k = 0; k < 4; ++k) {
            float4 alo = *(const float4*)&a_lds[k * ND + d0];
            float4 ahi = *(const float4*)&a_lds[k * ND + d0 + 4];
            bf16x8 r;
            r[0] = (__bf16)(hff[0] * alo.x); r[1] = (__bf16)(hff[1] * alo.y);
            r[2] = (__bf16)(hff[2] * alo.z); r[3] = (__bf16)(hff[3] * alo.w);
            r[4] = (__bf16)(hff[4] * ahi.x); r[5] = (__bf16)(hff[5] * ahi.y);
            r[6] = (__bf16)(hff[6] * ahi.z); r[7] = (__bf16)(hff[7] * ahi.w);
            hk[k] = r;
        }
        bf16x8 bfr[4];
        #pragma unroll
        for (int ct = 0; ct < 4; ++ct)
            bfr[ct] = *(const bf16x8*)&h_lds[(ct * 16 + (l & 15)) * HS + d0];
        __builtin_amdgcn_s_setprio(1);
        #pragma unroll
        for (int ct = 0; ct < 4; ++ct)
            #pragma unroll
            for (int k = 0; k < 4; ++k)
                acc[ct][k] = __builtin_amdgcn_mfma_f32_16x16x32_bf16(hk[k], bfr[ct], acc[ct][k], 0, 0, 0);
        __builtin_amdgcn_s_setprio(0);
    }

    // ---- select raw logit by adj, THEN one leakyrelu, THEN exp (no max-sub).
    //      sentinel: leaky(-9e15) = -1.8e15 -> exp = 0. ----
    #pragma unroll
    for (int ct = 0; ct < 4; ++ct)
        #pragma unroll
        for (int r = 0; r < 4; ++r) {
            int av = adjv[ct][r];
            float v = av == 1 ? acc[ct][0][r]
                    : av == 2 ? acc[ct][1][r]
                    : av == 3 ? acc[ct][2][r]
                    : av == 4 ? acc[ct][3][r] : -9.0e15f;
            v = fmaxf(v, 0.2f * v);
            float p = __expf(v);
            al_lds[(i0 + r) * AS + ct * 16 + (l & 15)] = (__bf16)p;
        }

    // ---- P fragments + rowsum via ones-MFMA: sacc[r] = sum_j p[i0+r][j] ----
    const int ia = w * 16 + (l & 15);
    bf16x8 aA0 = *(const bf16x8*)&al_lds[ia * AS + g8];
    bf16x8 aA1 = *(const bf16x8*)&al_lds[ia * AS + 32 + g8];
    bf16x8 ones;
    #pragma unroll
    for (int e = 0; e < 8; ++e) ones[e] = (__bf16)1.0f;
    f32x4 sacc = {0.f, 0.f, 0.f, 0.f};
    sacc = __builtin_amdgcn_mfma_f32_16x16x32_bf16(aA0, ones, sacc, 0, 0, 0);
    sacc = __builtin_amdgcn_mfma_f32_16x16x32_bf16(aA1, ones, sacc, 0, 0, 0);
    float inv[4];
    #pragma unroll
    for (int r = 0; r < 4; ++r) inv[r] = __builtin_amdgcn_rcpf(sacc[r]);

    // ---- PV: issue ALL 32 tr-reads, one wait, then 16 MFMAs + stores ----
    unsigned trb = (unsigned)(unsigned long long)(&h_tr[0])
                 + (unsigned)(((l & 15) << 3) + (g << 8));
    bf16x4 tr[8][4];
#define TRR(dst, off) asm volatile("ds_read_b64_tr_b16 %0, %1 offset:" #off : "=v"(dst) : "v"(trb));
    TRR(tr[0][0], 0)     TRR(tr[0][1], 128)   TRR(tr[0][2], 1024)  TRR(tr[0][3], 1152)
    TRR(tr[1][0], 2048)  TRR(tr[1][1], 2176)  TRR(tr[1][2], 3072)  TRR(tr[1][3], 3200)
    TRR(tr[2][0], 4096)  TRR(tr[2][1], 4224)  TRR(tr[2][2], 5120)  TRR(tr[2][3], 5248)
    TRR(tr[3][0], 6144)  TRR(tr[3][1], 6272)  TRR(tr[3][2], 7168)  TRR(tr[3][3], 7296)
    TRR(tr[4][0], 8192)  TRR(tr[4][1], 8320)  TRR(tr[4][2], 9216)  TRR(tr[4][3], 9344)
    TRR(tr[5][0], 10240) TRR(tr[5][1], 10368) TRR(tr[5][2], 11264) TRR(tr[5][3], 11392)
    TRR(tr[6][0], 12288) TRR(tr[6][1], 12416) TRR(tr[6][2], 13312) TRR(tr[6][3], 13440)
    TRR(tr[7][0], 14336) TRR(tr[7][1], 14464) TRR(tr[7][2], 15360) TRR(tr[7][3], 15488)
#undef TRR
    asm volatile("s_waitcnt lgkmcnt(0)" ::: "memory");
    __builtin_amdgcn_sched_barrier(0);

    float* outb = out + (size_t)b * NN * ND;
    #pragma unroll
    for (int dt = 0; dt < 8; ++dt) {
        bf16x8 B0 = __builtin_shufflevector(tr[dt][0], tr[dt][1], 0, 1, 2, 3, 4, 5, 6, 7);
        bf16x8 B1 = __builtin_shufflevector(tr[dt][2], tr[dt][3], 0, 1, 2, 3, 4, 5, 6, 7);
        __builtin_amdgcn_s_setprio(1);
        f32x4 o = {0.f, 0.f, 0.f, 0.f};
        o = __builtin_amdgcn_mfma_f32_16x16x32_bf16(aA0, B0, o, 0, 0, 0);
        o = __builtin_amdgcn_mfma_f32_16x16x32_bf16(aA1, B1, o, 0, 0, 0);
        __builtin_amdgcn_s_setprio(0);
        int dr = dt * 16 + (l & 15);
        #pragma unroll
        for (int r = 0; r < 4; ++r)
            outb[(i0 + r) * ND + dr] = o[r] * inv[r];
    }
}

extern "C" void kernel_launch(void* const* d_in, const int* in_sizes, int n_in,
                              void* d_out, int out_size, void* d_ws, size_t ws_size,
                              hipStream_t stream) {
    const float* hidden = (const float*)d_in[0];
    const int*   adj    = (const int*)d_in[1];
    const float* a      = (const float*)d_in[2];
    float*       out    = (float*)d_out;
    gat_kernel<<<NB, 256, 0, stream>>>(hidden, adj, a, out);
}